// Round 9
// baseline (193.296 us; speedup 1.0000x reference)
//
#include <hip/hip_runtime.h>
#include <hip/hip_fp16.h>

// NCC loss, v15: fused kernel, software-pipelined A||B with ONE barrier/round.
// v14 post-mortem: halving LDS instructions made it SLOWER (107 vs 93.3us,
// VALU 43->36%) -> LDS-issue model falsified. v10 pipe accounting: round
// 9.3k cy = 4.0k VALU + ~1.7k LDS + ~3.6k STALL (serial loads->slide->
// barrier->B->barrier at 16 waves/CU). Attack the stall, not op counts.
// v15 = v10 data path exactly (f32 sws, fp16 LDS ring, FCH=40, 76KB LDS,
// 2 blocks/CU), restructured: single-slice rounds, sws double-buffered as
// pipeline stages; per round: issue A-loads(s+1) -> B(s) from buf[s&1]
// (load latency hides under B) -> A slides+write buf[(s+1)&1] -> 1 barrier.
// A on dedicated waves 0-2 (192 thr, dense lanes). Same barrier COUNT as
// v10 (48) but B never waits on same-round A. Numerics identical -> absmax 0.
#define ND 2
#define DD 160
#define HH 192
#define WW 160
#define HW (HH * WW)
#define DHW (DD * HH * WW)

constexpr int TW  = 32;            // tile width  (outputs)
constexpr int TH  = 16;            // tile height (outputs) -> 512 columns
constexpr int HLO = TH + 8;        // 24 rows incl. H halo
constexpr int FCH = 40;            // d outputs per block
constexpr int NCH = DD / FCH;      // 4 chunks
constexpr int NSL = FCH + 8;       // 48 slices streamed (1 per round)

struct alignas(8) h4 { __half2 lo, hi; };

__device__ __forceinline__ void slide4(const float x[12], float S[4]) {
    float f = ((x[0] + x[1]) + (x[2] + x[3]))
            + ((x[4] + x[5]) + (x[6] + x[7])) + x[8];
    S[0] = f;
    f += x[9]  - x[0]; S[1] = f;
    f += x[10] - x[1]; S[2] = f;
    f += x[11] - x[2]; S[3] = f;
}

__global__ __launch_bounds__(512)
void ncc_fused5(const float* __restrict__ I, const float* __restrict__ J,
                float* __restrict__ outp)
{
    // pipeline-buffered stage-A output: centered W-sums (f32, v10 format)
    __shared__ float4 sws[2][HLO][TW + 1];          // 25,344 B
    __shared__ float  sw4[2][HLO][TW + 1];          //  6,336 B
    // D-ring: last 9 slices' centered HW-sums, fp16 (proven format)
    __shared__ h4     ring4[9][512];                // 36,864 B
    __shared__ __half ring1[9][512];                //  9,216 B
    __shared__ float  wred[8];

    const int tid = threadIdx.x;
    const int w0  = blockIdx.x * TW;                // 0..128
    const int h0  = blockIdx.y * TH;                // 0..176
    const int z   = blockIdx.z;                     // 0..7
    const int n   = z >> 2;
    const int d0  = (z & 3) * FCH;

    // ---- stage-A role: 192 jobs = 24 halo rows x 8 groups (waves 0..2) ----
    const bool ajob = (tid < 192);
    const int  arow = tid >> 3;                     // 0..23
    const int  awg  = tid & 7;                      // 0..7
    const int  agh  = h0 + arow - 4;
    const bool ahok = (agh >= 0) && (agh < HH);
    const int  agws = w0 + awg * 4 - 4;

    // ---- stage-B role: one (h,w) column per thread (all 512) ----
    const int oh = tid >> 5;                        // 0..15
    const int ow = tid & 31;                        // 0..31
    const int h  = h0 + oh, w = w0 + ow;
    const float cW  = (float)(min(w + 4, WW - 1) - max(w - 4, 0) + 1);
    const float cH  = (float)(min(h + 4, HH - 1) - max(h - 4, 0) + 1);
    const float cHW = cW * cH;

    // zero this thread's ring column
    {
        h4 zz; zz.lo = __floats2half2_rn(0.f, 0.f); zz.hi = zz.lo;
        const __half z1 = __float2half(0.f);
        #pragma unroll
        for (int q = 0; q < 9; ++q) { ring4[q][tid] = zz; ring1[q][tid] = z1; }
    }

    float run0 = 0.f, run1 = 0.f, run2 = 0.f, run3 = 0.f, run4 = 0.f;
    float acc = 0.f;
    const float inv = 1.0f / 729.0f;

    // prefetch registers (centered, zero-filled at boundaries)
    float pa[12], pb[12];
    auto load_ab = [&](int ss) {                    // slice index 0..NSL-1
        const int dd  = d0 - 4 + ss;
        const bool dok = (dd >= 0) && (dd < DD);
        const int rbase = (n * DD + dd) * HW + agh * WW;
        #pragma unroll
        for (int c = 0; c < 3; ++c) {
            const int gw = agws + 4 * c;
            float4 va = make_float4(0.f, 0.f, 0.f, 0.f), vb = va;
            if (dok && ahok && gw >= 0 && gw < WW) {
                va = *(const float4*)(I + rbase + gw);
                vb = *(const float4*)(J + rbase + gw);
                va.x -= 0.5f; va.y -= 0.5f; va.z -= 0.5f; va.w -= 0.5f;
                vb.x -= 0.5f; vb.y -= 0.5f; vb.z -= 0.5f; vb.w -= 0.5f;
            }
            *(float4*)&pa[4 * c] = va;
            *(float4*)&pb[4 * c] = vb;
        }
    };
    auto consume_store = [&](int ss) {              // slides + write buf[ss&1]
        const int dd = d0 - 4 + ss;
        if (dd >= 0 && dd < DD) {
            const int buf = ss & 1;
            float S0[4], S1[4], S2[4], S3[4], S4[4], f[12];
            slide4(pa, S0);
            slide4(pb, S1);
            #pragma unroll
            for (int i = 0; i < 12; ++i) f[i] = pa[i] * pa[i];
            slide4(f, S2);
            #pragma unroll
            for (int i = 0; i < 12; ++i) f[i] = pb[i] * pb[i];
            slide4(f, S3);
            #pragma unroll
            for (int i = 0; i < 12; ++i) f[i] = pa[i] * pb[i];
            slide4(f, S4);
            #pragma unroll
            for (int t = 0; t < 4; ++t) {
                sws[buf][arow][awg * 4 + t] =
                    make_float4(S0[t], S1[t], S2[t], S3[t]);
                sw4[buf][arow][awg * 4 + t] = S4[t];
            }
        }
    };

    // prologue: slice 0 into buf0
    if (ajob) { load_ab(0); consume_store(0); }
    __syncthreads();

    #pragma unroll 1
    for (int g = 0; g < 6; ++g) {                   // 6 x 9 = 54 >= NSL
        #pragma unroll
        for (int r = 0; r < 9; ++r) {
            const int rr = g * 9 + r;               // round = slice index
            if (rr < NSL) {
                // ---- issue next slice's global loads (fly under B) ----
                if (ajob && rr + 1 < NSL) load_ab(rr + 1);

                // ---- stage B(rr): taps from buf[rr&1] + ring + cc ----
                {
                    const int buf = rr & 1;
                    const int ddx = d0 - 4 + rr;
                    float t0 = 0.f, t1 = 0.f, t2 = 0.f, t3 = 0.f, t4 = 0.f;
                    if (ddx >= 0 && ddx < DD) {
                        #pragma unroll
                        for (int q = 0; q < 9; ++q) {
                            const float4 v = sws[buf][oh + q][ow];
                            t0 += v.x; t1 += v.y; t2 += v.z; t3 += v.w;
                            t4 += sw4[buf][oh + q][ow];
                        }
                    }
                    // round to fp16 (proven ws rounding), update ring + runs
                    h4 nh;
                    nh.lo = __floats2half2_rn(t0, t1);
                    nh.hi = __floats2half2_rn(t2, t3);
                    const __half n4h = __float2half(t4);
                    // rr % 9 == r (compile-time constant)
                    const h4     po = ring4[r][tid];
                    const __half p4 = ring1[r][tid];
                    run0 += __low2float(nh.lo)  - __low2float(po.lo);
                    run1 += __high2float(nh.lo) - __high2float(po.lo);
                    run2 += __low2float(nh.hi)  - __low2float(po.hi);
                    run3 += __high2float(nh.hi) - __high2float(po.hi);
                    run4 += __half2float(n4h)   - __half2float(p4);
                    ring4[r][tid] = nh;
                    ring1[r][tid] = n4h;
                    if (rr >= 8) {
                        const int d = d0 + rr - 8;
                        const float cD  = (float)(min(d + 4, DD - 1) - max(d - 4, 0) + 1);
                        const float cnt = cHW * cD;
                        // reconstruct uncentered box sums (exact algebra)
                        const float Is = run0 + 0.5f * cnt;
                        const float Js = run1 + 0.5f * cnt;
                        const float I2 = run2 + run0 + 0.25f * cnt;
                        const float J2 = run3 + run1 + 0.25f * cnt;
                        const float IJ = run4 + 0.5f * (run0 + run1) + 0.25f * cnt;
                        const float uI = Is * inv, uJ = Js * inv;
                        const float cross = IJ - uI * Js;
                        const float Iv = fmaxf(I2 - uI * Is, 1e-5f);
                        const float Jv = fmaxf(J2 - uJ * Js, 1e-5f);
                        acc += cross * cross / (Iv * Jv + 1e-5f);
                    }
                }

                // ---- stage A(rr+1): consume loads, write buf[(rr+1)&1] ----
                if (ajob && rr + 1 < NSL) consume_store(rr + 1);

                __syncthreads();                     // one barrier per round
            }
        }
    }

    // ---- block reduction, one fp32 atomic per block ----
    #pragma unroll
    for (int off = 32; off > 0; off >>= 1)
        acc += __shfl_down(acc, off, 64);
    const int lane = tid & 63, wid = tid >> 6;
    if (lane == 0) wred[wid] = acc;
    __syncthreads();
    if (tid == 0) {
        float ssum = 0.f;
        #pragma unroll
        for (int i = 0; i < 8; ++i) ssum += wred[i];
        atomicAdd(outp, -ssum);
    }
}

extern "C" void kernel_launch(void* const* d_in, const int* in_sizes, int n_in,
                              void* d_out, int out_size, void* d_ws, size_t ws_size,
                              hipStream_t stream)
{
    const float* I = (const float*)d_in[0];   // y_true
    const float* J = (const float*)d_in[1];   // y_pred
    float* out = (float*)d_out;

    hipMemsetAsync(out, 0, sizeof(float), stream);
    dim3 grid(WW / TW, HH / TH, ND * NCH);    // 5 x 12 x 8 = 480 blocks
    ncc_fused5<<<grid, 512, 0, stream>>>(I, J, out);
}

// Round 10
// 158.605 us; speedup vs baseline: 1.2187x; 1.2187x over previous
//
#include <hip/hip_runtime.h>
#include <hip/hip_fp16.h>

// NCC loss, v16: v10's proven structure + async global_load_lds input staging
// + ring diet (5 LDS slots + 4 reg slots).
// v15 post-mortem: VGPR=52 proved the compiler SANK the register prefetch
// (pa/pb never live across B) — source-level prefetch is un-keepable (m131+).
// global_load_lds is the one async mechanism it can't sink: DMA issued after
// bar1 (sraw free), drained at bar2's vmcnt(0) — the whole B-phase covers
// the HBM/L3 latency. A's loads become ds_reads of resident data.
// Round (= v10): [A(s,s+1) from sraw; bar1; DMA(s+2,s+3); B(s,s+1); bar2].
// 24 rounds x 2 barriers = 48 (v10 count). A values bit-identical to v10:
// DMA stages raw; A applies the original predicate (dok&&ahok&&gw in range)
// after ds_read, then centers. LDS 72KB -> 2 blocks/CU.
#define ND 2
#define DD 160
#define HH 192
#define WW 160
#define HW (HH * WW)
#define DHW (DD * HH * WW)

constexpr int TW  = 32;            // tile width  (outputs)
constexpr int TH  = 16;            // tile height (outputs) -> 512 columns
constexpr int HLO = TH + 8;        // 24 rows incl. H halo
constexpr int FCH = 40;            // d outputs per block
constexpr int NCH = DD / FCH;      // 4 chunks
constexpr int NSL = FCH + 8;       // 48 slices streamed
constexpr int NR  = NSL / 2;       // 24 rounds, 2 slices each

struct alignas(8) h4 { __half2 lo, hi; };

__device__ __forceinline__ void slide4(const float x[12], float S[4]) {
    float f = ((x[0] + x[1]) + (x[2] + x[3]))
            + ((x[4] + x[5]) + (x[6] + x[7])) + x[8];
    S[0] = f;
    f += x[9]  - x[0]; S[1] = f;
    f += x[10] - x[1]; S[2] = f;
    f += x[11] - x[2]; S[3] = f;
}

__global__ __launch_bounds__(512)
void ncc_fused6(const float* __restrict__ I, const float* __restrict__ J,
                float* __restrict__ outp)
{
    // raw input staging: per slice-slot an 8KB region:
    //   floats [0,960)    : I rows, 24 x 40 (row r at r*40)
    //   floats [960,1920) : J rows
    //   floats [1920,2048): pad (DMA overrun slots)
    __shared__ float  sraw[2][2048];                // 16,384 B
    // stage-A output: centered W-sums (f32, v10 format), 2 slices
    __shared__ float4 sws[2][HLO][TW + 1];          // 25,344 B
    __shared__ float  sw4[2][HLO][TW + 1];          //  6,336 B
    // D-ring, slots jj=0..4 in LDS (jj=5..8 live in registers)
    __shared__ h4     ring4[5][512];                // 20,480 B
    __shared__ __half ring1[5][512];                //  5,120 B
    __shared__ float  wred[8];                      // total 73,696 B

    const int tid = threadIdx.x;
    const int w0  = blockIdx.x * TW;                // 0..128
    const int h0  = blockIdx.y * TH;                // 0..176
    const int z   = blockIdx.z;                     // 0..7
    const int n   = z >> 2;
    const int d0  = (z & 3) * FCH;

    // ---- stage-A role: 384 jobs = 2 slices x 24 rows x 8 groups ----
    const bool ajob = (tid < 384);
    const int  sl   = tid / 192;                    // slice-of-round (0/1)
    const int  rj   = tid - sl * 192;
    const int  arow = rj >> 3;                      // 0..23
    const int  awg  = rj & 7;                       // 0..7
    const int  agh  = h0 + arow - 4;
    const bool ahok = (agh >= 0) && (agh < HH);
    const int  agws = w0 + awg * 4 - 4;

    // ---- stage-B role: one (h,w) column per thread (all 512) ----
    const int oh = tid >> 5;                        // 0..15
    const int ow = tid & 31;                        // 0..31
    const int h  = h0 + oh, w = w0 + ow;
    const float cW  = (float)(min(w + 4, WW - 1) - max(w - 4, 0) + 1);
    const float cH  = (float)(min(h + 4, HH - 1) - max(h - 4, 0) + 1);
    const float cHW = cW * cH;

    // ---- DMA role: chunk `tid` of each slice region (round-invariant) ----
    const bool chI   = tid < 240;
    const bool chPad = tid >= 480;
    const int  cr    = chI ? tid : (tid - 240);     // 0..239 when real
    const int  crow  = cr / 10, cwc = cr - crow * 10;
    const int  cgh   = h0 + crow - 4;
    const int  cgw   = w0 - 4 + cwc * 4;
    const bool spok  = !chPad && cgh >= 0 && cgh < HH && cgw >= 0 && cgw < WW;
    const float* fptr = chI ? I : J;
    const int  spoff = spok ? (cgh * WW + cgw) : 0;
    // wave-uniform LDS dest base: chunk (tid & ~63), lane adds l*16
    const int  ldsbase = (tid & ~63) * 4;           // float index

    auto stage = [&](int p, int dd) {               // DMA one slice -> sraw[p]
        const bool dok = (dd >= 0) && (dd < DD);
        const float* src = (dok && spok)
            ? (fptr + (size_t)(n * DD + dd) * HW + spoff)
            : fptr;                                  // clamped-safe address
        __builtin_amdgcn_global_load_lds(
            (const __attribute__((address_space(1))) void*)src,
            (__attribute__((address_space(3))) void*)&sraw[p][ldsbase],
            16, 0, 0);
    };

    // zero LDS ring slots + register ring slots
    h4 rg5, rg6, rg7, rg8; __half rs5, rs6, rs7, rs8;
    {
        h4 zz; zz.lo = __floats2half2_rn(0.f, 0.f); zz.hi = zz.lo;
        const __half z1 = __float2half(0.f);
        #pragma unroll
        for (int q = 0; q < 5; ++q) { ring4[q][tid] = zz; ring1[q][tid] = z1; }
        rg5 = rg6 = rg7 = rg8 = zz;
        rs5 = rs6 = rs7 = rs8 = z1;
    }

    float run0 = 0.f, run1 = 0.f, run2 = 0.f, run3 = 0.f, run4 = 0.f;
    float acc = 0.f;
    const float inv = 1.0f / 729.0f;

    // prologue: stage slices 0,1 of this chunk
    stage(0, d0 - 4 + 0);
    stage(1, d0 - 4 + 1);
    __syncthreads();                                 // drains DMA (vmcnt 0)

    #pragma unroll 1
    for (int g = 0; g < 3; ++g) {                    // 3 x 9 = 27 >= NR
        #pragma unroll
        for (int r = 0; r < 9; ++r) {
            const int rr = g * 9 + r;
            if (rr < NR) {
                const int s0  = 2 * rr;
                const int dd0 = d0 - 4 + s0;
                // ---- stage A: slides from LDS-resident raw rows ----
                if (ajob) {
                    const int dd = dd0 + sl;
                    const bool dok = (dd >= 0) && (dd < DD);
                    float a[12], b[12];
                    const int fi = arow * 40 + awg * 4;
                    #pragma unroll
                    for (int c = 0; c < 3; ++c) {
                        const int gw = agws + 4 * c;
                        float4 va = *(const float4*)&sraw[sl][fi + 4 * c];
                        float4 vb = *(const float4*)&sraw[sl][960 + fi + 4 * c];
                        if (dok && ahok && gw >= 0 && gw < WW) {
                            va.x -= 0.5f; va.y -= 0.5f; va.z -= 0.5f; va.w -= 0.5f;
                            vb.x -= 0.5f; vb.y -= 0.5f; vb.z -= 0.5f; vb.w -= 0.5f;
                        } else {
                            va = make_float4(0.f, 0.f, 0.f, 0.f); vb = va;
                        }
                        *(float4*)&a[4 * c] = va;
                        *(float4*)&b[4 * c] = vb;
                    }
                    if (dok) {
                        float S0[4], S1[4], S2[4], S3[4], S4[4], f[12];
                        slide4(a, S0);
                        slide4(b, S1);
                        #pragma unroll
                        for (int i = 0; i < 12; ++i) f[i] = a[i] * a[i];
                        slide4(f, S2);
                        #pragma unroll
                        for (int i = 0; i < 12; ++i) f[i] = b[i] * b[i];
                        slide4(f, S3);
                        #pragma unroll
                        for (int i = 0; i < 12; ++i) f[i] = a[i] * b[i];
                        slide4(f, S4);
                        #pragma unroll
                        for (int t = 0; t < 4; ++t) {
                            sws[sl][arow][awg * 4 + t] =
                                make_float4(S0[t], S1[t], S2[t], S3[t]);
                            sw4[sl][arow][awg * 4 + t] = S4[t];
                        }
                    }
                }
                __syncthreads();                     // bar1: sws ready, sraw free
                // ---- DMA next round's slices (lands by bar2) ----
                if (rr + 1 < NR) {
                    stage(0, dd0 + 2);
                    stage(1, dd0 + 3);
                }
                // ---- stage B: taps + ring (hybrid) + cc ----
                #pragma unroll
                for (int half = 0; half < 2; ++half) {
                    const int s   = s0 + half;
                    const int ddx = dd0 + half;
                    float t0 = 0.f, t1 = 0.f, t2 = 0.f, t3 = 0.f, t4 = 0.f;
                    if (ddx >= 0 && ddx < DD) {
                        #pragma unroll
                        for (int q = 0; q < 9; ++q) {
                            const float4 v = sws[half][oh + q][ow];
                            t0 += v.x; t1 += v.y; t2 += v.z; t3 += v.w;
                            t4 += sw4[half][oh + q][ow];
                        }
                    }
                    h4 nh;
                    nh.lo = __floats2half2_rn(t0, t1);
                    nh.hi = __floats2half2_rn(t2, t3);
                    const __half n4h = __float2half(t4);
                    const int jj = (2 * r + half) % 9;   // literal after unroll
                    h4 po; __half p4;
                    if (jj < 5)       { po = ring4[jj][tid]; p4 = ring1[jj][tid]; }
                    else if (jj == 5) { po = rg5; p4 = rs5; }
                    else if (jj == 6) { po = rg6; p4 = rs6; }
                    else if (jj == 7) { po = rg7; p4 = rs7; }
                    else              { po = rg8; p4 = rs8; }
                    run0 += __low2float(nh.lo)  - __low2float(po.lo);
                    run1 += __high2float(nh.lo) - __high2float(po.lo);
                    run2 += __low2float(nh.hi)  - __low2float(po.hi);
                    run3 += __high2float(nh.hi) - __high2float(po.hi);
                    run4 += __half2float(n4h)   - __half2float(p4);
                    if (jj < 5)       { ring4[jj][tid] = nh; ring1[jj][tid] = n4h; }
                    else if (jj == 5) { rg5 = nh; rs5 = n4h; }
                    else if (jj == 6) { rg6 = nh; rs6 = n4h; }
                    else if (jj == 7) { rg7 = nh; rs7 = n4h; }
                    else              { rg8 = nh; rs8 = n4h; }
                    if (s >= 8) {
                        const int d = d0 + s - 8;
                        const float cD  = (float)(min(d + 4, DD - 1) - max(d - 4, 0) + 1);
                        const float cnt = cHW * cD;
                        // reconstruct uncentered box sums (exact algebra)
                        const float Is = run0 + 0.5f * cnt;
                        const float Js = run1 + 0.5f * cnt;
                        const float I2 = run2 + run0 + 0.25f * cnt;
                        const float J2 = run3 + run1 + 0.25f * cnt;
                        const float IJ = run4 + 0.5f * (run0 + run1) + 0.25f * cnt;
                        const float uI = Is * inv, uJ = Js * inv;
                        const float cross = IJ - uI * Js;
                        const float Iv = fmaxf(I2 - uI * Is, 1e-5f);
                        const float Jv = fmaxf(J2 - uJ * Js, 1e-5f);
                        acc += cross * cross / (Iv * Jv + 1e-5f);
                    }
                }
                __syncthreads();                     // bar2: drains DMA vmcnt
            }
        }
    }

    // ---- block reduction, one fp32 atomic per block ----
    #pragma unroll
    for (int off = 32; off > 0; off >>= 1)
        acc += __shfl_down(acc, off, 64);
    const int lane = tid & 63, wid = tid >> 6;
    if (lane == 0) wred[wid] = acc;
    __syncthreads();
    if (tid == 0) {
        float ssum = 0.f;
        #pragma unroll
        for (int i = 0; i < 8; ++i) ssum += wred[i];
        atomicAdd(outp, -ssum);
    }
}

extern "C" void kernel_launch(void* const* d_in, const int* in_sizes, int n_in,
                              void* d_out, int out_size, void* d_ws, size_t ws_size,
                              hipStream_t stream)
{
    const float* I = (const float*)d_in[0];   // y_true
    const float* J = (const float*)d_in[1];   // y_pred
    float* out = (float*)d_out;

    hipMemsetAsync(out, 0, sizeof(float), stream);
    dim3 grid(WW / TW, HH / TH, ND * NCH);    // 5 x 12 x 8 = 480 blocks
    ncc_fused6<<<grid, 512, 0, stream>>>(I, J, out);
}